// Round 1
// baseline (209.306 us; speedup 1.0000x reference)
//
#include <hip/hip_runtime.h>
#include <math.h>

// Problem constants
#define MIN_T   0.01f
#define MAX_T   0.5f
#define LESION_T 0.3f

constexpr int VOX             = 128 * 128 * 128;   // 2,097,152 voxels per batch
constexpr int F4_PER_BATCH    = VOX / 4;           // 524,288 float4s
constexpr int THREADS         = 256;
constexpr int BLOCKS_PER_BATCH = 256;
constexpr int F4_PER_BLOCK    = F4_PER_BATCH / BLOCKS_PER_BATCH; // 2048
constexpr int ITERS           = F4_PER_BLOCK / THREADS;          // 8
constexpr int NB              = 16;                // batches
constexpr int NACC            = 8;                 // accumulators per batch

// Accumulator layout per batch (doubles):
// 0: cnt(>MIN_T)  1: cnt(>MAX_T)  2: sum|d-diff|  3: sum|h-diff|
// 4: sum|w-diff|  5: sum s*mask   6: sum s^2*mask 7: cnt(>LESION_T)
__global__ __launch_bounds__(THREADS)
void partial_kernel(const float* __restrict__ pred, double* __restrict__ acc)
{
    const int b   = blockIdx.y;
    const int blk = blockIdx.x;
    const float* __restrict__ s = pred + (size_t)b * VOX;
    const float4* __restrict__ s4 = reinterpret_cast<const float4*>(s);

    float cnt_min = 0.f, cnt_max = 0.f, sum_d = 0.f, sum_h = 0.f,
          sum_w = 0.f, sm = 0.f, sm2 = 0.f, les = 0.f;

    #pragma unroll
    for (int k = 0; k < ITERS; ++k) {
        const int f4 = blk * F4_PER_BLOCK + k * THREADS + (int)threadIdx.x;
        const int i  = f4 * 4;                 // flat voxel index within batch
        const int w0 = i & 127;                // 0,4,...,124
        const int h  = (i >> 7) & 127;
        const int d  = i >> 14;

        const float4 v = s4[f4];

        // element-wise stats
        {
            const float xs[4] = { v.x, v.y, v.z, v.w };
            #pragma unroll
            for (int j = 0; j < 4; ++j) {
                const float x  = xs[j];
                const float mk = (x > MIN_T) ? 1.0f : 0.0f;
                cnt_min += mk;
                cnt_max += (x > MAX_T)    ? 1.0f : 0.0f;
                les     += (x > LESION_T) ? 1.0f : 0.0f;
                sm      += x * mk;
                sm2     += x * x * mk;
            }
        }

        // w-direction diffs (3 intra-vector + 1 cross-vector)
        sum_w += fabsf(v.y - v.x) + fabsf(v.z - v.y) + fabsf(v.w - v.z);
        if (w0 < 124) {
            const float nx = s[i + 4];
            sum_w += fabsf(nx - v.w);
        }
        // h-direction diffs (+1 row = +128 floats = +32 float4s)
        if (h < 127) {
            const float4 vh = s4[f4 + 32];
            sum_h += fabsf(vh.x - v.x) + fabsf(vh.y - v.y) +
                     fabsf(vh.z - v.z) + fabsf(vh.w - v.w);
        }
        // d-direction diffs (+1 plane = +16384 floats = +4096 float4s)
        if (d < 127) {
            const float4 vd = s4[f4 + 4096];
            sum_d += fabsf(vd.x - v.x) + fabsf(vd.y - v.y) +
                     fabsf(vd.z - v.z) + fabsf(vd.w - v.w);
        }
    }

    // wave (64-lane) shuffle reduction, then LDS across 4 waves
    float vals[NACC] = { cnt_min, cnt_max, sum_d, sum_h, sum_w, sm, sm2, les };
    #pragma unroll
    for (int vi = 0; vi < NACC; ++vi) {
        float x = vals[vi];
        #pragma unroll
        for (int off = 32; off > 0; off >>= 1)
            x += __shfl_down(x, off, 64);
        vals[vi] = x;
    }

    __shared__ float smem[4][NACC];
    const int wave = threadIdx.x >> 6;
    const int lane = threadIdx.x & 63;
    if (lane == 0) {
        #pragma unroll
        for (int vi = 0; vi < NACC; ++vi) smem[wave][vi] = vals[vi];
    }
    __syncthreads();
    if (threadIdx.x < NACC) {
        const float t = smem[0][threadIdx.x] + smem[1][threadIdx.x] +
                        smem[2][threadIdx.x] + smem[3][threadIdx.x];
        atomicAdd(&acc[(size_t)b * NACC + threadIdx.x], (double)t);
    }
}

__global__ __launch_bounds__(64)
void finalize_kernel(const double* __restrict__ acc, float* __restrict__ out)
{
    float l = 0.0f;
    if (threadIdx.x < NB) {
        const double* a = acc + (size_t)threadIdx.x * NACC;
        const double cnt    = a[0];
        const double cntmax = a[1];
        const double sd     = a[2];
        const double sh     = a[3];
        const double sw     = a[4];
        const double sm     = a[5];
        const double sm2    = a[6];
        const double les    = a[7];

        const double inv_vox = 1.0 / (double)VOX;
        const double act  = cnt    * inv_vox;
        const double high = cntmax * inv_vox;

        double loss = fmax(0.005 - act, 0.0) * 15.0      // W_MIN
                    + fmax(high - 0.03, 0.0) * 5.0;      // W_MAX

        // gradient means: diff arrays have 127*128*128 elements each
        const double grad_den = 127.0 * 128.0 * 128.0;   // 2,080,768
        const double avg_grad = (sd + sh + sw) / (3.0 * grad_den);
        if (les > 0.5)
            loss += fmin(avg_grad, 1.0) * 5.0;           // W_CONT

        const double cnt_safe = fmax(cnt, 1.0);
        const double m  = sm / cnt_safe;
        double sq = sm2 - 2.0 * m * sm + m * m * cnt;
        if (sq < 0.0) sq = 0.0;

        const bool gate = (act > 0.001) && (cnt > 1.0);
        if (gate) {
            const double var     = sq / fmax(cnt - 1.0, 1.0);
            const double rel_std = sqrt(var) / (m + 1e-6);
            loss += exp(-5.0 * rel_std) * 7.0;           // W_SIZE
        }
        l = (float)loss;
    }
    #pragma unroll
    for (int off = 32; off > 0; off >>= 1)
        l += __shfl_down(l, off, 64);
    if (threadIdx.x == 0)
        out[0] = l / (float)NB;
}

extern "C" void kernel_launch(void* const* d_in, const int* in_sizes, int n_in,
                              void* d_out, int out_size, void* d_ws, size_t ws_size,
                              hipStream_t stream)
{
    const float* pred = (const float*)d_in[0];
    float* out        = (float*)d_out;
    double* acc       = (double*)d_ws;

    // zero the per-batch accumulators (workspace is poisoned before each call)
    hipMemsetAsync(d_ws, 0, (size_t)NB * NACC * sizeof(double), stream);

    dim3 grid(BLOCKS_PER_BATCH, NB);
    partial_kernel<<<grid, THREADS, 0, stream>>>(pred, acc);
    finalize_kernel<<<1, 64, 0, stream>>>(acc, out);
}

// Round 2
// 192.925 us; speedup vs baseline: 1.0849x; 1.0849x over previous
//
#include <hip/hip_runtime.h>
#include <math.h>

#define MIN_T    0.01f
#define MAX_T    0.5f
#define LESION_T 0.3f

constexpr int NB       = 16;
constexpr int DIM      = 128;
constexpr int PLANE_F4 = DIM * DIM / 4;        // 4096 float4 per plane
constexpr int VOX      = DIM * DIM * DIM;      // 2,097,152
constexpr int THREADS  = 256;
constexpr int HWBLKS   = PLANE_F4 / THREADS;   // 16 row-slabs (8 rows each)
constexpr int DSEGS    = 4;                    // d-axis segments
constexpr int DPS      = DIM / DSEGS;          // 32 planes per segment
constexpr int NACC     = 8;

// Accumulator layout per batch (doubles):
// 0: cnt(>MIN_T)  1: cnt(>MAX_T)  2: sum|d-diff|  3: sum|h-diff|
// 4: sum|w-diff|  5: sum s*mask   6: sum s^2*mask 7: cnt(>LESION_T)
__global__ __launch_bounds__(THREADS)
void partial_kernel(const float* __restrict__ pred, double* __restrict__ acc)
{
    const int seg   = blockIdx.x;
    const int hwblk = blockIdx.y;
    const int b     = blockIdx.z;
    const int tid   = (int)threadIdx.x;

    const float4* __restrict__ s4 =
        reinterpret_cast<const float4*>(pred + (size_t)b * VOX);

    // thread owns float4 at (h = hwblk*8 + tid/32, w4 = tid%32) on every plane
    const int  h    = hwblk * 8 + (tid >> 5);
    const bool do_h = (h < DIM - 1);            // h-pair (h,h+1) exists
    const bool do_w = ((tid & 31) != 31);       // w-cross pair exists (not row end)

    const int d0    = seg * DPS;
    const int d_end = (seg == DSEGS - 1) ? (DIM - 1) : (d0 + DPS);

    float cnt_min = 0.f, cnt_max = 0.f, sum_d = 0.f, sum_h = 0.f,
          sum_w = 0.f, sm = 0.f, sm2 = 0.f, les = 0.f;

    // stats + w/h diffs for one element (its plane's float4)
    auto process = [&](const float4& v, const float4& vh) {
        const float xs[4] = { v.x, v.y, v.z, v.w };
        #pragma unroll
        for (int j = 0; j < 4; ++j) {
            const float x  = xs[j];
            const float mk = (x > MIN_T) ? 1.0f : 0.0f;
            cnt_min += mk;
            cnt_max += (x > MAX_T)    ? 1.0f : 0.0f;
            les     += (x > LESION_T) ? 1.0f : 0.0f;
            sm      += x * mk;
            sm2     += x * x * mk;
        }
        sum_w += fabsf(v.y - v.x) + fabsf(v.z - v.y) + fabsf(v.w - v.z);
        const float nx = __shfl_down(v.x, 1, 64);   // next float4's .x (same row)
        if (do_w) sum_w += fabsf(nx - v.w);
        if (do_h) sum_h += fabsf(vh.x - v.x) + fabsf(vh.y - v.y)
                         + fabsf(vh.z - v.z) + fabsf(vh.w - v.w);
    };

    const float4 zero4 = { 0.f, 0.f, 0.f, 0.f };
    size_t base = (size_t)d0 * PLANE_F4 + hwblk * THREADS + tid;
    float4 v  = s4[base];
    float4 vh = do_h ? s4[base + 32] : zero4;

    // pairs (d-1, d) for d in [d0+1, d_end]; stats for planes d0 .. d_end-1
    for (int d = d0 + 1; d <= d_end; ++d) {
        base += PLANE_F4;
        const float4 nv  = s4[base];                       // prefetch next plane
        const float4 nvh = do_h ? s4[base + 32] : zero4;
        process(v, vh);
        sum_d += fabsf(nv.x - v.x) + fabsf(nv.y - v.y)
               + fabsf(nv.z - v.z) + fabsf(nv.w - v.w);
        v = nv; vh = nvh;
    }
    if (seg == DSEGS - 1)       // plane 127's element stats (not a d-pair source)
        process(v, vh);

    // wave (64-lane) shuffle reduction, then LDS across 4 waves
    float vals[NACC] = { cnt_min, cnt_max, sum_d, sum_h, sum_w, sm, sm2, les };
    #pragma unroll
    for (int vi = 0; vi < NACC; ++vi) {
        float x = vals[vi];
        #pragma unroll
        for (int off = 32; off > 0; off >>= 1)
            x += __shfl_down(x, off, 64);
        vals[vi] = x;
    }

    __shared__ float smem[4][NACC];
    const int wave = tid >> 6;
    const int lane = tid & 63;
    if (lane == 0) {
        #pragma unroll
        for (int vi = 0; vi < NACC; ++vi) smem[wave][vi] = vals[vi];
    }
    __syncthreads();
    if (tid < NACC) {
        const float t = smem[0][tid] + smem[1][tid] +
                        smem[2][tid] + smem[3][tid];
        atomicAdd(&acc[(size_t)b * NACC + tid], (double)t);
    }
}

__global__ __launch_bounds__(64)
void finalize_kernel(const double* __restrict__ acc, float* __restrict__ out)
{
    float l = 0.0f;
    if (threadIdx.x < NB) {
        const double* a = acc + (size_t)threadIdx.x * NACC;
        const double cnt    = a[0];
        const double cntmax = a[1];
        const double sd     = a[2];
        const double sh     = a[3];
        const double sw     = a[4];
        const double sm     = a[5];
        const double sm2    = a[6];
        const double les    = a[7];

        const double inv_vox = 1.0 / (double)VOX;
        const double act  = cnt    * inv_vox;
        const double high = cntmax * inv_vox;

        double loss = fmax(0.005 - act, 0.0) * 15.0      // W_MIN
                    + fmax(high - 0.03, 0.0) * 5.0;      // W_MAX

        const double grad_den = 127.0 * 128.0 * 128.0;   // diff-array size
        const double avg_grad = (sd + sh + sw) / (3.0 * grad_den);
        if (les > 0.5)
            loss += fmin(avg_grad, 1.0) * 5.0;           // W_CONT

        const double cnt_safe = fmax(cnt, 1.0);
        const double m  = sm / cnt_safe;
        double sq = sm2 - 2.0 * m * sm + m * m * cnt;
        if (sq < 0.0) sq = 0.0;

        const bool gate = (act > 0.001) && (cnt > 1.0);
        if (gate) {
            const double var     = sq / fmax(cnt - 1.0, 1.0);
            const double rel_std = sqrt(var) / (m + 1e-6);
            loss += exp(-5.0 * rel_std) * 7.0;           // W_SIZE
        }
        l = (float)loss;
    }
    #pragma unroll
    for (int off = 32; off > 0; off >>= 1)
        l += __shfl_down(l, off, 64);
    if (threadIdx.x == 0)
        out[0] = l / (float)NB;
}

extern "C" void kernel_launch(void* const* d_in, const int* in_sizes, int n_in,
                              void* d_out, int out_size, void* d_ws, size_t ws_size,
                              hipStream_t stream)
{
    const float* pred = (const float*)d_in[0];
    float* out        = (float*)d_out;
    double* acc       = (double*)d_ws;

    hipMemsetAsync(d_ws, 0, (size_t)NB * NACC * sizeof(double), stream);

    dim3 grid(DSEGS, HWBLKS, NB);
    partial_kernel<<<grid, THREADS, 0, stream>>>(pred, acc);
    finalize_kernel<<<1, 64, 0, stream>>>(acc, out);
}